// Round 2
// baseline (12537.368 us; speedup 1.0000x reference)
//
#include <hip/hip_runtime.h>

// ---------------------------------------------------------------------------
// TeacherModel: small U-Net + pose heads. B=8, H=W=384, fp32 NCHW.
// Round 2: fit workspace. Fused u2+seg (u2 never materialized) + d1 recompute
// cuts ws extent 377MB -> 216MiB. R1 abort was a GPU page fault (ws overflow).
// ---------------------------------------------------------------------------

#define BS 256

// Generic 3x3 stride-1 SAME conv, optional relu.
// Input = concat([maybe-up2(inA) (Ca ch), inB (Cb ch)], channel dim).
// UPA: 1 = inA is full-res HxW; 2 = inA is (H/2)x(W/2), nearest-up2.
// Each thread computes 4 adjacent x outputs for ONE output channel.
template <int UPA>
__global__ __launch_bounds__(BS) void conv3x3_kernel(
    const float* __restrict__ inA, int Ca,
    const float* __restrict__ inB, int Cb,
    const float* __restrict__ w, const float* __restrict__ b,
    float* __restrict__ out,
    int N, int H, int W, int Cout, int do_relu)
{
    const int Wq = W >> 2;
    int idx = blockIdx.x * BS + threadIdx.x;
    int total = N * Cout * H * Wq;
    if (idx >= total) return;
    int x4 = idx % Wq;
    int t  = idx / Wq;
    int y  = t % H;  t /= H;
    int co = t % Cout;
    int n  = t / Cout;
    int x0 = x4 << 2;
    const bool left_ok  = (x0 > 0);
    const bool right_ok = (x0 + 4 < W);
    const int Cin = Ca + Cb;

    float bias = b[co];
    float acc0 = bias, acc1 = bias, acc2 = bias, acc3 = bias;
    const float* wco = w + (size_t)co * Cin * 9;

    // ---- part A (possibly up2) ----
    for (int ci = 0; ci < Ca; ++ci) {
        const float* wc = wco + ci * 9;
#pragma unroll
        for (int ky = 0; ky < 3; ++ky) {
            int iy = y + ky - 1;
            if (iy < 0 || iy >= H) continue;
            float v0, v1, v2, v3, v4, v5;
            if (UPA == 2) {
                const float* r = inA + ((size_t)(n * Ca + ci) * (H >> 1) + (iy >> 1)) * (W >> 1);
                int xh = x0 >> 1;
                float sm = left_ok  ? r[xh - 1] : 0.f;
                float s0 = r[xh];
                float s1 = r[xh + 1];
                float s2 = right_ok ? r[xh + 2] : 0.f;
                v0 = sm; v1 = s0; v2 = s0; v3 = s1; v4 = s1; v5 = s2;
            } else {
                const float* r = inA + ((size_t)(n * Ca + ci) * H + iy) * W;
                v0 = left_ok ? r[x0 - 1] : 0.f;
                float4 q = *(const float4*)(r + x0);
                v1 = q.x; v2 = q.y; v3 = q.z; v4 = q.w;
                v5 = right_ok ? r[x0 + 4] : 0.f;
            }
            float w0 = wc[ky * 3 + 0], w1 = wc[ky * 3 + 1], w2 = wc[ky * 3 + 2];
            acc0 += w0 * v0 + w1 * v1 + w2 * v2;
            acc1 += w0 * v1 + w1 * v2 + w2 * v3;
            acc2 += w0 * v2 + w1 * v3 + w2 * v4;
            acc3 += w0 * v3 + w1 * v4 + w2 * v5;
        }
    }
    // ---- part B (skip connection, full res) ----
    for (int cb = 0; cb < Cb; ++cb) {
        const float* wc = wco + (Ca + cb) * 9;
#pragma unroll
        for (int ky = 0; ky < 3; ++ky) {
            int iy = y + ky - 1;
            if (iy < 0 || iy >= H) continue;
            const float* r = inB + ((size_t)(n * Cb + cb) * H + iy) * W;
            float v0 = left_ok ? r[x0 - 1] : 0.f;
            float4 q = *(const float4*)(r + x0);
            float v1 = q.x, v2 = q.y, v3 = q.z, v4 = q.w;
            float v5 = right_ok ? r[x0 + 4] : 0.f;
            float w0 = wc[ky * 3 + 0], w1 = wc[ky * 3 + 1], w2 = wc[ky * 3 + 2];
            acc0 += w0 * v0 + w1 * v1 + w2 * v2;
            acc1 += w0 * v1 + w1 * v2 + w2 * v3;
            acc2 += w0 * v2 + w1 * v3 + w2 * v4;
            acc3 += w0 * v3 + w1 * v4 + w2 * v5;
        }
    }
    if (do_relu) {
        acc0 = fmaxf(acc0, 0.f); acc1 = fmaxf(acc1, 0.f);
        acc2 = fmaxf(acc2, 0.f); acc3 = fmaxf(acc3, 0.f);
    }
    float4 o; o.x = acc0; o.y = acc1; o.z = acc2; o.w = acc3;
    *(float4*)(out + ((size_t)(n * Cout + co) * H + y) * W + x0) = o;
}

// Fused: u2 = relu(conv3x3(concat(up2(u1), d1); 96->32)); seg = conv1x1(u2; 32->1)
// u2 is never materialized. Each thread: 2 pixels x all 32 co channels.
__global__ __launch_bounds__(BS) void u2seg_kernel(
    const float* __restrict__ u1,    // [N,64,H/2,W/2]
    const float* __restrict__ d1,    // [N,32,H,W]
    const float* __restrict__ w_u2,  // [32,96,3,3]
    const float* __restrict__ b_u2,  // [32]
    const float* __restrict__ w_seg, // [32]
    const float* __restrict__ b_seg, // [1]
    float* __restrict__ seg,         // [N,1,H,W]
    int N, int H, int W)
{
    const int Wh = W >> 1;
    int idx = blockIdx.x * BS + threadIdx.x;
    int total = N * H * Wh;
    if (idx >= total) return;
    int xp = idx % Wh;
    int t  = idx / Wh;
    int y  = t % H;
    int n  = t / H;
    int x0 = xp << 1;
    const bool left_ok  = (x0 > 0);
    const bool right_ok = (x0 + 2 < W);
    const int H2 = H >> 1, W2 = W >> 1;

    float acc[64];
#pragma unroll
    for (int co = 0; co < 32; ++co) {
        float bv = b_u2[co];
        acc[2 * co] = bv; acc[2 * co + 1] = bv;
    }

    // window v[ky][0..3] corresponds to input x = x0-1, x0, x0+1, x0+2
    // ---- part A: up2(u1), 64 channels at half res ----
    for (int ci = 0; ci < 64; ++ci) {
        float v[3][4];
#pragma unroll
        for (int ky = 0; ky < 3; ++ky) {
            int iy = y + ky - 1;
            if (iy < 0 || iy >= H) {
                v[ky][0] = v[ky][1] = v[ky][2] = v[ky][3] = 0.f;
                continue;
            }
            const float* r = u1 + ((size_t)(n * 64 + ci) * H2 + (iy >> 1)) * W2;
            int xh = x0 >> 1;
            float sm = left_ok  ? r[xh - 1] : 0.f;
            float s0 = r[xh];
            float s1 = right_ok ? r[xh + 1] : 0.f;
            v[ky][0] = sm; v[ky][1] = s0; v[ky][2] = s0; v[ky][3] = s1;
        }
        const float* wc = w_u2 + ci * 9;
#pragma unroll
        for (int co = 0; co < 32; ++co) {
            const float* wp = wc + co * (96 * 9);
#pragma unroll
            for (int ky = 0; ky < 3; ++ky) {
                float w0 = wp[ky * 3 + 0], w1 = wp[ky * 3 + 1], w2 = wp[ky * 3 + 2];
                acc[2 * co]     += w0 * v[ky][0] + w1 * v[ky][1] + w2 * v[ky][2];
                acc[2 * co + 1] += w0 * v[ky][1] + w1 * v[ky][2] + w2 * v[ky][3];
            }
        }
    }
    // ---- part B: d1 skip, 32 channels full res (weight ci = 64+cb) ----
    for (int cb = 0; cb < 32; ++cb) {
        float v[3][4];
#pragma unroll
        for (int ky = 0; ky < 3; ++ky) {
            int iy = y + ky - 1;
            if (iy < 0 || iy >= H) {
                v[ky][0] = v[ky][1] = v[ky][2] = v[ky][3] = 0.f;
                continue;
            }
            const float* r = d1 + ((size_t)(n * 32 + cb) * H + iy) * W;
            v[ky][0] = left_ok ? r[x0 - 1] : 0.f;
            float2 q = *(const float2*)(r + x0);
            v[ky][1] = q.x; v[ky][2] = q.y;
            v[ky][3] = right_ok ? r[x0 + 2] : 0.f;
        }
        const float* wc = w_u2 + (64 + cb) * 9;
#pragma unroll
        for (int co = 0; co < 32; ++co) {
            const float* wp = wc + co * (96 * 9);
#pragma unroll
            for (int ky = 0; ky < 3; ++ky) {
                float w0 = wp[ky * 3 + 0], w1 = wp[ky * 3 + 1], w2 = wp[ky * 3 + 2];
                acc[2 * co]     += w0 * v[ky][0] + w1 * v[ky][1] + w2 * v[ky][2];
                acc[2 * co + 1] += w0 * v[ky][1] + w1 * v[ky][2] + w2 * v[ky][3];
            }
        }
    }
    // relu + 1x1 seg
    float s0 = b_seg[0], s1 = b_seg[0];
#pragma unroll
    for (int co = 0; co < 32; ++co) {
        float wv = w_seg[co];
        s0 += wv * fmaxf(acc[2 * co], 0.f);
        s1 += wv * fmaxf(acc[2 * co + 1], 0.f);
    }
    float2 o; o.x = s0; o.y = s1;
    *(float2*)(seg + ((size_t)n * H + y) * W + x0) = o;
}

// 2x2 maxpool stride 2
__global__ __launch_bounds__(BS) void maxpool2_kernel(
    const float* __restrict__ in, float* __restrict__ out, int NC, int H, int W)
{
    int Ho = H >> 1, Wo = W >> 1;
    int idx = blockIdx.x * BS + threadIdx.x;
    int total = NC * Ho * Wo;
    if (idx >= total) return;
    int x = idx % Wo;
    int t = idx / Wo;
    int y = t % Ho;
    int c = t / Ho;
    const float* r0 = in + ((size_t)c * H + 2 * y) * W + 2 * x;
    const float* r1 = r0 + W;
    out[idx] = fmaxf(fmaxf(r0[0], r0[1]), fmaxf(r1[0], r1[1]));
}

// 3x3 stride-2 SAME conv (pad_lo=0, pad_hi=1), input = concat([inA, inB])
__global__ __launch_bounds__(BS) void conv3x3_s2_kernel(
    const float* __restrict__ inA, int Ca,
    const float* __restrict__ inB, int Cb,
    const float* __restrict__ w, const float* __restrict__ b,
    float* __restrict__ out,
    int N, int Hi, int Wi, int Cout, int do_relu)
{
    int Ho = Hi >> 1, Wo = Wi >> 1;
    int idx = blockIdx.x * BS + threadIdx.x;
    int total = N * Cout * Ho * Wo;
    if (idx >= total) return;
    int ox = idx % Wo;
    int t  = idx / Wo;
    int oy = t % Ho; t /= Ho;
    int co = t % Cout;
    int n  = t / Cout;
    const int Cin = Ca + Cb;
    float acc = b[co];
    const float* wco = w + (size_t)co * Cin * 9;

    for (int ci = 0; ci < Cin; ++ci) {
        const float* base = (ci < Ca)
            ? inA + (size_t)(n * Ca + ci) * Hi * Wi
            : inB + (size_t)(n * Cb + (ci - Ca)) * Hi * Wi;
        const float* wc = wco + ci * 9;
#pragma unroll
        for (int ky = 0; ky < 3; ++ky) {
            int iy = 2 * oy + ky;           // pad_lo = 0
            if (iy >= Hi) continue;
#pragma unroll
            for (int kx = 0; kx < 3; ++kx) {
                int ix = 2 * ox + kx;
                if (ix >= Wi) continue;
                acc += wc[ky * 3 + kx] * base[(size_t)iy * Wi + ix];
            }
        }
    }
    if (do_relu) acc = fmaxf(acc, 0.f);
    out[((size_t)(n * Cout + co) * Ho + oy) * Wo + ox] = acc;
}

// 1x1 conv, 4 pixels per thread
__global__ __launch_bounds__(BS) void conv1x1_kernel(
    const float* __restrict__ in, const float* __restrict__ w,
    const float* __restrict__ b, float* __restrict__ out,
    int N, int Cin, int HW, int Cout, int do_relu)
{
    int HWq = HW >> 2;
    int idx = blockIdx.x * BS + threadIdx.x;
    int total = N * Cout * HWq;
    if (idx >= total) return;
    int q  = idx % HWq;
    int t  = idx / HWq;
    int co = t % Cout;
    int n  = t / Cout;
    float bias = b[co];
    float a0 = bias, a1 = bias, a2 = bias, a3 = bias;
    const float* wc = w + (size_t)co * Cin;
    const float* base = in + (size_t)n * Cin * HW + 4 * q;
    for (int ci = 0; ci < Cin; ++ci) {
        float4 v = *(const float4*)(base + (size_t)ci * HW);
        float wv = wc[ci];
        a0 += wv * v.x; a1 += wv * v.y; a2 += wv * v.z; a3 += wv * v.w;
    }
    if (do_relu) {
        a0 = fmaxf(a0, 0.f); a1 = fmaxf(a1, 0.f);
        a2 = fmaxf(a2, 0.f); a3 = fmaxf(a3, 0.f);
    }
    float4 o; o.x = a0; o.y = a1; o.z = a2; o.w = a3;
    *(float4*)(out + ((size_t)(n * Cout + co)) * HW + 4 * q) = o;
}

// local-max peaks mask: interior strict > thresh, >= 4-neighbors; border = 0
__global__ __launch_bounds__(BS) void peaks_kernel(
    const float* __restrict__ hm, float* __restrict__ out,
    int NC, int H, int W, float thresh)
{
    int idx = blockIdx.x * BS + threadIdx.x;
    int total = NC * H * W;
    if (idx >= total) return;
    int x = idx % W;
    int t = idx / W;
    int y = t % H;
    int c = t / H;
    float r = 0.f;
    if (x >= 1 && x < W - 1 && y >= 1 && y < H - 1) {
        const float* base = hm + (size_t)c * H * W;
        float cv = base[y * W + x];
        if (cv > thresh &&
            cv >= base[(y - 1) * W + x] &&
            cv >= base[(y + 1) * W + x] &&
            cv >= base[y * W + (x - 1)] &&
            cv >= base[y * W + (x + 1)])
            r = 1.f;
    }
    out[idx] = r;
}

static inline int nblk(long n) { return (int)((n + BS - 1) / BS); }

extern "C" void kernel_launch(void* const* d_in, const int* in_sizes, int n_in,
                              void* d_out, int out_size, void* d_ws, size_t ws_size,
                              hipStream_t stream)
{
    const float* x     = (const float*)d_in[0];
    const float* w_d1  = (const float*)d_in[1];  const float* b_d1  = (const float*)d_in[2];
    const float* w_d2  = (const float*)d_in[3];  const float* b_d2  = (const float*)d_in[4];
    const float* w_bn  = (const float*)d_in[5];  const float* b_bn  = (const float*)d_in[6];
    const float* w_u1  = (const float*)d_in[7];  const float* b_u1  = (const float*)d_in[8];
    const float* w_u2  = (const float*)d_in[9];  const float* b_u2  = (const float*)d_in[10];
    const float* w_seg = (const float*)d_in[11]; const float* b_seg = (const float*)d_in[12];
    const float* w_p1  = (const float*)d_in[13]; const float* b_p1  = (const float*)d_in[14];
    const float* w_p2  = (const float*)d_in[15]; const float* b_p2  = (const float*)d_in[16];
    const float* w_hm  = (const float*)d_in[17]; const float* b_hm  = (const float*)d_in[18];
    const float* w_paf = (const float*)d_in[19]; const float* b_paf = (const float*)d_in[20];

    const int N = 8, H = 384, W = 384;
    const int H2 = 192, W2 = 192, H4 = 96, W4 = 96;

    float* ws = (float*)d_ws;
    // Workspace layout (floats), extent = 56,623,104 floats = 216 MiB.
    // Region map with lifetimes (no producer/consumer overlap at any step):
    //  step1 d1   -> [18874368, 56623104)  reads x
    //  step2 pd1  -> [0, 9437184)          reads d1   (d1 dead after)
    //  step3 d2   -> [18874368, 37748736)  reads pd1  (overwrites dead d1; pd1 dead after)
    //  step4 pd2  -> [47185920, 51904512)  reads d2
    //  step5 bn   -> [37748736, 47185920)  reads pd2  (pd2 dead after... after u1 input? no: bn only)
    //  step6 u1   -> [0, 18874368)         reads bn + d2 (both dead after; overwrites dead pd1)
    //  step7 d1'  -> [18874368, 56623104)  reads x    (overwrites dead d2/bn/pd2)
    //  step8 u2seg-> seg in d_out          reads u1 + d1'
    //  step9 p1   -> [0, 18874368)         reads x + seg (overwrites dead u1)
    //  step10 p2  -> [18874368, 28311552)  reads p1
    float* u1  = ws;                   // 8*64*192*192 = 18874368
    float* d1  = ws + 18874368;        // 8*32*384*384 = 37748736 (also d1' recompute)
    float* d2  = ws + 18874368;        // 8*64*192*192 = 18874368
    float* bn  = ws + 37748736;        // 8*128*96*96  = 9437184
    float* pd1 = ws;                   // 8*32*192*192 = 9437184
    float* pd2 = ws + 47185920;        // 8*64*96*96   = 4718592
    float* p1  = ws;                   // 8*64*192*192 = 18874368
    float* p2  = ws + 18874368;        // 8*128*96*96  = 9437184

    float* out_seg   = (float*)d_out;                 // 8*1*384*384   = 1179648
    float* out_hm    = out_seg + 1179648;             // 8*17*96*96    = 1253376
    float* out_paf   = out_hm + 1253376;              // 8*32*96*96    = 2359296
    float* out_peaks = out_paf + 2359296;             // 8*17*96*96    = 1253376

    // 1. d1 = relu(conv3x3(x; 3->32)) @384
    conv3x3_kernel<1><<<nblk((long)N * 32 * H * (W / 4)), BS, 0, stream>>>(
        x, 3, nullptr, 0, w_d1, b_d1, d1, N, H, W, 32, 1);
    // 2. pd1 = maxpool(d1) @192
    maxpool2_kernel<<<nblk((long)N * 32 * H2 * W2), BS, 0, stream>>>(d1, pd1, N * 32, H, W);
    // 3. d2 = relu(conv3x3(pd1; 32->64)) @192   (overwrites dead d1)
    conv3x3_kernel<1><<<nblk((long)N * 64 * H2 * (W2 / 4)), BS, 0, stream>>>(
        pd1, 32, nullptr, 0, w_d2, b_d2, d2, N, H2, W2, 64, 1);
    // 4. pd2 = maxpool(d2) @96
    maxpool2_kernel<<<nblk((long)N * 64 * H4 * W4), BS, 0, stream>>>(d2, pd2, N * 64, H2, W2);
    // 5. bn = relu(conv3x3(pd2; 64->128)) @96
    conv3x3_kernel<1><<<nblk((long)N * 128 * H4 * (W4 / 4)), BS, 0, stream>>>(
        pd2, 64, nullptr, 0, w_bn, b_bn, bn, N, H4, W4, 128, 1);
    // 6. u1 = relu(conv3x3(concat(up2(bn), d2); 192->64)) @192
    conv3x3_kernel<2><<<nblk((long)N * 64 * H2 * (W2 / 4)), BS, 0, stream>>>(
        bn, 128, d2, 64, w_u1, b_u1, u1, N, H2, W2, 64, 1);
    // 7. d1' = relu(conv3x3(x; 3->32)) @384  (recompute, ~2 GFLOP)
    conv3x3_kernel<1><<<nblk((long)N * 32 * H * (W / 4)), BS, 0, stream>>>(
        x, 3, nullptr, 0, w_d1, b_d1, d1, N, H, W, 32, 1);
    // 8. seg = conv1x1(relu(conv3x3(concat(up2(u1), d1); 96->32)); 32->1)  [fused]
    u2seg_kernel<<<nblk((long)N * H * (W / 2)), BS, 0, stream>>>(
        u1, d1, w_u2, b_u2, w_seg, b_seg, out_seg, N, H, W);
    // 9. p1 = relu(conv3x3_s2(concat(x, seg); 4->64)) @384->192
    conv3x3_s2_kernel<<<nblk((long)N * 64 * H2 * W2), BS, 0, stream>>>(
        x, 3, out_seg, 1, w_p1, b_p1, p1, N, H, W, 64, 1);
    // 10. p2 = relu(conv3x3_s2(p1; 64->128)) @192->96
    conv3x3_s2_kernel<<<nblk((long)N * 128 * H4 * W4), BS, 0, stream>>>(
        p1, 64, nullptr, 0, w_p2, b_p2, p2, N, H2, W2, 128, 1);
    // 11. hm = conv1x1(p2; 128->17) @96
    conv1x1_kernel<<<nblk((long)N * 17 * (H4 * W4 / 4)), BS, 0, stream>>>(
        p2, w_hm, b_hm, out_hm, N, 128, H4 * W4, 17, 0);
    // 12. paf = conv1x1(p2; 128->32) @96
    conv1x1_kernel<<<nblk((long)N * 32 * (H4 * W4 / 4)), BS, 0, stream>>>(
        p2, w_paf, b_paf, out_paf, N, 128, H4 * W4, 32, 0);
    // 13. peaks @96
    peaks_kernel<<<nblk((long)N * 17 * H4 * W4), BS, 0, stream>>>(
        out_hm, out_peaks, N * 17, H4, W4, 0.1f);
}

// Round 3
// 3475.320 us; speedup vs baseline: 3.6075x; 3.6075x over previous
//
#include <hip/hip_runtime.h>

// ---------------------------------------------------------------------------
// TeacherModel: small U-Net + pose heads. B=8, H=W=384, fp32 NCHW.
// Round 3: co-blocked register tiling (TCO=8) for all 3x3 convs, co block in
// blockIdx.y so weights are wave-uniform (scalar loads). Vectorized maxpool.
// R2 counters: all convs latency-bound (VALUBusy 16-34%) from no input reuse.
// ---------------------------------------------------------------------------

#define BS 256

// 3x3 stride-1 SAME conv, TCO output channels per thread, 4 px per thread.
// Input = concat([maybe-up2(inA) (Ca ch), inB (Cb ch)]).
// UPA: 1 = inA full-res; 2 = inA half-res nearest-up2.
template <int UPA, int TCO>
__global__ __launch_bounds__(BS) void conv3x3_co_kernel(
    const float* __restrict__ inA, int Ca,
    const float* __restrict__ inB, int Cb,
    const float* __restrict__ w, const float* __restrict__ b,
    float* __restrict__ out,
    int N, int H, int W, int Cout, int do_relu)
{
    const int Wq = W >> 2;
    int idx = blockIdx.x * BS + threadIdx.x;
    int total = N * H * Wq;
    if (idx >= total) return;
    int x4 = idx % Wq;
    int t  = idx / Wq;
    int y  = t % H;
    int n  = t / H;
    int x0 = x4 << 2;
    const int co0 = blockIdx.y * TCO;       // wave-uniform
    const bool left_ok  = (x0 > 0);
    const bool right_ok = (x0 + 4 < W);
    const int Cin = Ca + Cb;

    float acc[TCO][4];
#pragma unroll
    for (int j = 0; j < TCO; ++j) {
        float bv = b[co0 + j];
        acc[j][0] = bv; acc[j][1] = bv; acc[j][2] = bv; acc[j][3] = bv;
    }

    for (int ci = 0; ci < Cin; ++ci) {
        // window v[ky][0..5] = input x0-1 .. x0+4
        float v[3][6];
#pragma unroll
        for (int ky = 0; ky < 3; ++ky) {
            int iy = y + ky - 1;
            if (iy < 0 || iy >= H) {
                v[ky][0] = v[ky][1] = v[ky][2] = v[ky][3] = v[ky][4] = v[ky][5] = 0.f;
                continue;
            }
            if (UPA == 2 && ci < Ca) {
                const float* r = inA + ((size_t)(n * Ca + ci) * (H >> 1) + (iy >> 1)) * (W >> 1);
                int xh = x0 >> 1;
                float sm = left_ok  ? r[xh - 1] : 0.f;
                float s0 = r[xh];
                float s1 = r[xh + 1];
                float s2 = right_ok ? r[xh + 2] : 0.f;
                v[ky][0] = sm; v[ky][1] = s0; v[ky][2] = s0;
                v[ky][3] = s1; v[ky][4] = s1; v[ky][5] = s2;
            } else {
                const float* r = (ci < Ca)
                    ? inA + ((size_t)(n * Ca + ci) * H + iy) * W
                    : inB + ((size_t)(n * Cb + (ci - Ca)) * H + iy) * W;
                v[ky][0] = left_ok ? r[x0 - 1] : 0.f;
                float4 q = *(const float4*)(r + x0);
                v[ky][1] = q.x; v[ky][2] = q.y; v[ky][3] = q.z; v[ky][4] = q.w;
                v[ky][5] = right_ok ? r[x0 + 4] : 0.f;
            }
        }
#pragma unroll
        for (int j = 0; j < TCO; ++j) {
            const float* wp = w + ((size_t)(co0 + j) * Cin + ci) * 9;  // uniform -> s_load
#pragma unroll
            for (int ky = 0; ky < 3; ++ky) {
                float w0 = wp[ky * 3 + 0], w1 = wp[ky * 3 + 1], w2 = wp[ky * 3 + 2];
#pragma unroll
                for (int p = 0; p < 4; ++p)
                    acc[j][p] += w0 * v[ky][p] + w1 * v[ky][p + 1] + w2 * v[ky][p + 2];
            }
        }
    }

#pragma unroll
    for (int j = 0; j < TCO; ++j) {
        float4 o;
        o.x = acc[j][0]; o.y = acc[j][1]; o.z = acc[j][2]; o.w = acc[j][3];
        if (do_relu) {
            o.x = fmaxf(o.x, 0.f); o.y = fmaxf(o.y, 0.f);
            o.z = fmaxf(o.z, 0.f); o.w = fmaxf(o.w, 0.f);
        }
        *(float4*)(out + ((size_t)(n * Cout + co0 + j) * H + y) * W + x0) = o;
    }
}

// 3x3 stride-2 SAME conv (pad_lo=0, pad_hi=1), TCO cos x 4 out-px per thread.
template <int TCO>
__global__ __launch_bounds__(BS) void conv3x3_s2_co_kernel(
    const float* __restrict__ inA, int Ca,
    const float* __restrict__ inB, int Cb,
    const float* __restrict__ w, const float* __restrict__ b,
    float* __restrict__ out,
    int N, int Hi, int Wi, int Cout, int do_relu)
{
    const int Ho = Hi >> 1, Wo = Wi >> 1, Woq = Wo >> 2;
    int idx = blockIdx.x * BS + threadIdx.x;
    int total = N * Ho * Woq;
    if (idx >= total) return;
    int q  = idx % Woq;
    int t  = idx / Woq;
    int oy = t % Ho;
    int n  = t / Ho;
    int ox0 = q << 2;
    int ix0 = ox0 << 1;                       // input x start (pad_lo = 0)
    const int co0 = blockIdx.y * TCO;
    const bool right_ok = (ix0 + 8 < Wi);
    const int Cin = Ca + Cb;

    float acc[TCO][4];
#pragma unroll
    for (int j = 0; j < TCO; ++j) {
        float bv = b[co0 + j];
        acc[j][0] = bv; acc[j][1] = bv; acc[j][2] = bv; acc[j][3] = bv;
    }

    for (int ci = 0; ci < Cin; ++ci) {
        const float* base = (ci < Ca)
            ? inA + (size_t)(n * Ca + ci) * Hi * Wi
            : inB + (size_t)(n * Cb + (ci - Ca)) * Hi * Wi;
        // window v[ky][0..8] = input ix0 .. ix0+8
        float v[3][9];
#pragma unroll
        for (int ky = 0; ky < 3; ++ky) {
            int iy = 2 * oy + ky;
            if (iy >= Hi) {
                v[ky][0]=v[ky][1]=v[ky][2]=v[ky][3]=v[ky][4]=v[ky][5]=v[ky][6]=v[ky][7]=v[ky][8]=0.f;
                continue;
            }
            const float* r = base + (size_t)iy * Wi + ix0;
            float4 a = *(const float4*)r;
            float4 c = *(const float4*)(r + 4);
            v[ky][0] = a.x; v[ky][1] = a.y; v[ky][2] = a.z; v[ky][3] = a.w;
            v[ky][4] = c.x; v[ky][5] = c.y; v[ky][6] = c.z; v[ky][7] = c.w;
            v[ky][8] = right_ok ? r[8] : 0.f;
        }
#pragma unroll
        for (int j = 0; j < TCO; ++j) {
            const float* wp = w + ((size_t)(co0 + j) * Cin + ci) * 9;  // uniform
#pragma unroll
            for (int ky = 0; ky < 3; ++ky) {
                float w0 = wp[ky * 3 + 0], w1 = wp[ky * 3 + 1], w2 = wp[ky * 3 + 2];
#pragma unroll
                for (int p = 0; p < 4; ++p)
                    acc[j][p] += w0 * v[ky][2 * p] + w1 * v[ky][2 * p + 1] + w2 * v[ky][2 * p + 2];
            }
        }
    }

#pragma unroll
    for (int j = 0; j < TCO; ++j) {
        float4 o;
        o.x = acc[j][0]; o.y = acc[j][1]; o.z = acc[j][2]; o.w = acc[j][3];
        if (do_relu) {
            o.x = fmaxf(o.x, 0.f); o.y = fmaxf(o.y, 0.f);
            o.z = fmaxf(o.z, 0.f); o.w = fmaxf(o.w, 0.f);
        }
        *(float4*)(out + ((size_t)(n * Cout + co0 + j) * Ho + oy) * Wo + ox0) = o;
    }
}

// Fused: u2 = relu(conv3x3(concat(up2(u1), d1); 96->32)); seg = conv1x1(u2; 32->1)
__global__ __launch_bounds__(BS) void u2seg_kernel(
    const float* __restrict__ u1,    // [N,64,H/2,W/2]
    const float* __restrict__ d1,    // [N,32,H,W]
    const float* __restrict__ w_u2,  // [32,96,3,3]
    const float* __restrict__ b_u2,  // [32]
    const float* __restrict__ w_seg, // [32]
    const float* __restrict__ b_seg, // [1]
    float* __restrict__ seg,         // [N,1,H,W]
    int N, int H, int W)
{
    const int Wh = W >> 1;
    int idx = blockIdx.x * BS + threadIdx.x;
    int total = N * H * Wh;
    if (idx >= total) return;
    int xp = idx % Wh;
    int t  = idx / Wh;
    int y  = t % H;
    int n  = t / H;
    int x0 = xp << 1;
    const bool left_ok  = (x0 > 0);
    const bool right_ok = (x0 + 2 < W);
    const int H2 = H >> 1, W2 = W >> 1;

    float acc[64];
#pragma unroll
    for (int co = 0; co < 32; ++co) {
        float bv = b_u2[co];
        acc[2 * co] = bv; acc[2 * co + 1] = bv;
    }

    for (int ci = 0; ci < 64; ++ci) {
        float v[3][4];
#pragma unroll
        for (int ky = 0; ky < 3; ++ky) {
            int iy = y + ky - 1;
            if (iy < 0 || iy >= H) {
                v[ky][0] = v[ky][1] = v[ky][2] = v[ky][3] = 0.f;
                continue;
            }
            const float* r = u1 + ((size_t)(n * 64 + ci) * H2 + (iy >> 1)) * W2;
            int xh = x0 >> 1;
            float sm = left_ok  ? r[xh - 1] : 0.f;
            float s0 = r[xh];
            float s1 = right_ok ? r[xh + 1] : 0.f;
            v[ky][0] = sm; v[ky][1] = s0; v[ky][2] = s0; v[ky][3] = s1;
        }
        const float* wc = w_u2 + ci * 9;
#pragma unroll
        for (int co = 0; co < 32; ++co) {
            const float* wp = wc + co * (96 * 9);
#pragma unroll
            for (int ky = 0; ky < 3; ++ky) {
                float w0 = wp[ky * 3 + 0], w1 = wp[ky * 3 + 1], w2 = wp[ky * 3 + 2];
                acc[2 * co]     += w0 * v[ky][0] + w1 * v[ky][1] + w2 * v[ky][2];
                acc[2 * co + 1] += w0 * v[ky][1] + w1 * v[ky][2] + w2 * v[ky][3];
            }
        }
    }
    for (int cb = 0; cb < 32; ++cb) {
        float v[3][4];
#pragma unroll
        for (int ky = 0; ky < 3; ++ky) {
            int iy = y + ky - 1;
            if (iy < 0 || iy >= H) {
                v[ky][0] = v[ky][1] = v[ky][2] = v[ky][3] = 0.f;
                continue;
            }
            const float* r = d1 + ((size_t)(n * 32 + cb) * H + iy) * W;
            v[ky][0] = left_ok ? r[x0 - 1] : 0.f;
            float2 qq = *(const float2*)(r + x0);
            v[ky][1] = qq.x; v[ky][2] = qq.y;
            v[ky][3] = right_ok ? r[x0 + 2] : 0.f;
        }
        const float* wc = w_u2 + (64 + cb) * 9;
#pragma unroll
        for (int co = 0; co < 32; ++co) {
            const float* wp = wc + co * (96 * 9);
#pragma unroll
            for (int ky = 0; ky < 3; ++ky) {
                float w0 = wp[ky * 3 + 0], w1 = wp[ky * 3 + 1], w2 = wp[ky * 3 + 2];
                acc[2 * co]     += w0 * v[ky][0] + w1 * v[ky][1] + w2 * v[ky][2];
                acc[2 * co + 1] += w0 * v[ky][1] + w1 * v[ky][2] + w2 * v[ky][3];
            }
        }
    }
    float s0 = b_seg[0], s1 = b_seg[0];
#pragma unroll
    for (int co = 0; co < 32; ++co) {
        float wv = w_seg[co];
        s0 += wv * fmaxf(acc[2 * co], 0.f);
        s1 += wv * fmaxf(acc[2 * co + 1], 0.f);
    }
    float2 o; o.x = s0; o.y = s1;
    *(float2*)(seg + ((size_t)n * H + y) * W + x0) = o;
}

// 2x2 maxpool stride 2, float4-vectorized output
__global__ __launch_bounds__(BS) void maxpool2_kernel(
    const float* __restrict__ in, float* __restrict__ out, int NC, int H, int W)
{
    int Ho = H >> 1, Wo = W >> 1, Woq = Wo >> 2;
    int idx = blockIdx.x * BS + threadIdx.x;
    int total = NC * Ho * Woq;
    if (idx >= total) return;
    int x4 = idx % Woq;
    int t  = idx / Woq;
    int y  = t % Ho;
    int c  = t / Ho;
    const float* r0 = in + ((size_t)c * H + 2 * y) * W + 8 * x4;
    const float* r1 = r0 + W;
    float4 a0 = *(const float4*)r0;
    float4 a1 = *(const float4*)(r0 + 4);
    float4 b0 = *(const float4*)r1;
    float4 b1 = *(const float4*)(r1 + 4);
    float4 o;
    o.x = fmaxf(fmaxf(a0.x, a0.y), fmaxf(b0.x, b0.y));
    o.y = fmaxf(fmaxf(a0.z, a0.w), fmaxf(b0.z, b0.w));
    o.z = fmaxf(fmaxf(a1.x, a1.y), fmaxf(b1.x, b1.y));
    o.w = fmaxf(fmaxf(a1.z, a1.w), fmaxf(b1.z, b1.w));
    *(float4*)(out + ((size_t)c * Ho + y) * Wo + 4 * x4) = o;
}

// 1x1 conv, 4 pixels per thread
__global__ __launch_bounds__(BS) void conv1x1_kernel(
    const float* __restrict__ in, const float* __restrict__ w,
    const float* __restrict__ b, float* __restrict__ out,
    int N, int Cin, int HW, int Cout, int do_relu)
{
    int HWq = HW >> 2;
    int idx = blockIdx.x * BS + threadIdx.x;
    int total = N * Cout * HWq;
    if (idx >= total) return;
    int q  = idx % HWq;
    int t  = idx / HWq;
    int co = t % Cout;
    int n  = t / Cout;
    float bias = b[co];
    float a0 = bias, a1 = bias, a2 = bias, a3 = bias;
    const float* wc = w + (size_t)co * Cin;
    const float* base = in + (size_t)n * Cin * HW + 4 * q;
    for (int ci = 0; ci < Cin; ++ci) {
        float4 v = *(const float4*)(base + (size_t)ci * HW);
        float wv = wc[ci];
        a0 += wv * v.x; a1 += wv * v.y; a2 += wv * v.z; a3 += wv * v.w;
    }
    if (do_relu) {
        a0 = fmaxf(a0, 0.f); a1 = fmaxf(a1, 0.f);
        a2 = fmaxf(a2, 0.f); a3 = fmaxf(a3, 0.f);
    }
    float4 o; o.x = a0; o.y = a1; o.z = a2; o.w = a3;
    *(float4*)(out + ((size_t)(n * Cout + co)) * HW + 4 * q) = o;
}

// local-max peaks mask
__global__ __launch_bounds__(BS) void peaks_kernel(
    const float* __restrict__ hm, float* __restrict__ out,
    int NC, int H, int W, float thresh)
{
    int idx = blockIdx.x * BS + threadIdx.x;
    int total = NC * H * W;
    if (idx >= total) return;
    int x = idx % W;
    int t = idx / W;
    int y = t % H;
    int c = t / H;
    float r = 0.f;
    if (x >= 1 && x < W - 1 && y >= 1 && y < H - 1) {
        const float* base = hm + (size_t)c * H * W;
        float cv = base[y * W + x];
        if (cv > thresh &&
            cv >= base[(y - 1) * W + x] &&
            cv >= base[(y + 1) * W + x] &&
            cv >= base[y * W + (x - 1)] &&
            cv >= base[y * W + (x + 1)])
            r = 1.f;
    }
    out[idx] = r;
}

static inline int nblk(long n) { return (int)((n + BS - 1) / BS); }

extern "C" void kernel_launch(void* const* d_in, const int* in_sizes, int n_in,
                              void* d_out, int out_size, void* d_ws, size_t ws_size,
                              hipStream_t stream)
{
    const float* x     = (const float*)d_in[0];
    const float* w_d1  = (const float*)d_in[1];  const float* b_d1  = (const float*)d_in[2];
    const float* w_d2  = (const float*)d_in[3];  const float* b_d2  = (const float*)d_in[4];
    const float* w_bn  = (const float*)d_in[5];  const float* b_bn  = (const float*)d_in[6];
    const float* w_u1  = (const float*)d_in[7];  const float* b_u1  = (const float*)d_in[8];
    const float* w_u2  = (const float*)d_in[9];  const float* b_u2  = (const float*)d_in[10];
    const float* w_seg = (const float*)d_in[11]; const float* b_seg = (const float*)d_in[12];
    const float* w_p1  = (const float*)d_in[13]; const float* b_p1  = (const float*)d_in[14];
    const float* w_p2  = (const float*)d_in[15]; const float* b_p2  = (const float*)d_in[16];
    const float* w_hm  = (const float*)d_in[17]; const float* b_hm  = (const float*)d_in[18];
    const float* w_paf = (const float*)d_in[19]; const float* b_paf = (const float*)d_in[20];

    const int N = 8, H = 384, W = 384;
    const int H2 = 192, W2 = 192, H4 = 96, W4 = 96;

    float* ws = (float*)d_ws;
    // Workspace extent = 56,623,104 floats = 216 MiB (see R2 lifetime map).
    float* u1  = ws;                   // 8*64*192*192 = 18874368
    float* d1  = ws + 18874368;        // 8*32*384*384 = 37748736 (also d1' recompute)
    float* d2  = ws + 18874368;        // 8*64*192*192 = 18874368
    float* bn  = ws + 37748736;        // 8*128*96*96  = 9437184
    float* pd1 = ws;                   // 8*32*192*192 = 9437184
    float* pd2 = ws + 47185920;        // 8*64*96*96   = 4718592
    float* p1  = ws;                   // 8*64*192*192 = 18874368
    float* p2  = ws + 18874368;        // 8*128*96*96  = 9437184

    float* out_seg   = (float*)d_out;                 // 8*1*384*384   = 1179648
    float* out_hm    = out_seg + 1179648;             // 8*17*96*96    = 1253376
    float* out_paf   = out_hm + 1253376;              // 8*32*96*96    = 2359296
    float* out_peaks = out_paf + 2359296;             // 8*17*96*96    = 1253376

    // 1. d1 = relu(conv3x3(x; 3->32)) @384
    {
        dim3 g(nblk((long)N * H * (W / 4)), 32 / 8);
        conv3x3_co_kernel<1, 8><<<g, BS, 0, stream>>>(
            x, 3, nullptr, 0, w_d1, b_d1, d1, N, H, W, 32, 1);
    }
    // 2. pd1 = maxpool(d1) @192
    maxpool2_kernel<<<nblk((long)N * 32 * H2 * (W2 / 4)), BS, 0, stream>>>(d1, pd1, N * 32, H, W);
    // 3. d2 = relu(conv3x3(pd1; 32->64)) @192
    {
        dim3 g(nblk((long)N * H2 * (W2 / 4)), 64 / 8);
        conv3x3_co_kernel<1, 8><<<g, BS, 0, stream>>>(
            pd1, 32, nullptr, 0, w_d2, b_d2, d2, N, H2, W2, 64, 1);
    }
    // 4. pd2 = maxpool(d2) @96
    maxpool2_kernel<<<nblk((long)N * 64 * H4 * (W4 / 4)), BS, 0, stream>>>(d2, pd2, N * 64, H2, W2);
    // 5. bn = relu(conv3x3(pd2; 64->128)) @96
    {
        dim3 g(nblk((long)N * H4 * (W4 / 4)), 128 / 8);
        conv3x3_co_kernel<1, 8><<<g, BS, 0, stream>>>(
            pd2, 64, nullptr, 0, w_bn, b_bn, bn, N, H4, W4, 128, 1);
    }
    // 6. u1 = relu(conv3x3(concat(up2(bn), d2); 192->64)) @192
    {
        dim3 g(nblk((long)N * H2 * (W2 / 4)), 64 / 8);
        conv3x3_co_kernel<2, 8><<<g, BS, 0, stream>>>(
            bn, 128, d2, 64, w_u1, b_u1, u1, N, H2, W2, 64, 1);
    }
    // 7. d1' = relu(conv3x3(x; 3->32)) @384  (recompute)
    {
        dim3 g(nblk((long)N * H * (W / 4)), 32 / 8);
        conv3x3_co_kernel<1, 8><<<g, BS, 0, stream>>>(
            x, 3, nullptr, 0, w_d1, b_d1, d1, N, H, W, 32, 1);
    }
    // 8. seg = fused u2+seg
    u2seg_kernel<<<nblk((long)N * H * (W / 2)), BS, 0, stream>>>(
        u1, d1, w_u2, b_u2, w_seg, b_seg, out_seg, N, H, W);
    // 9. p1 = relu(conv3x3_s2(concat(x, seg); 4->64)) @384->192
    {
        dim3 g(nblk((long)N * H2 * (W2 / 4)), 64 / 8);
        conv3x3_s2_co_kernel<8><<<g, BS, 0, stream>>>(
            x, 3, out_seg, 1, w_p1, b_p1, p1, N, H, W, 64, 1);
    }
    // 10. p2 = relu(conv3x3_s2(p1; 64->128)) @192->96
    {
        dim3 g(nblk((long)N * H4 * (W4 / 4)), 128 / 8);
        conv3x3_s2_co_kernel<8><<<g, BS, 0, stream>>>(
            p1, 64, nullptr, 0, w_p2, b_p2, p2, N, H2, W2, 128, 1);
    }
    // 11. hm = conv1x1(p2; 128->17) @96
    conv1x1_kernel<<<nblk((long)N * 17 * (H4 * W4 / 4)), BS, 0, stream>>>(
        p2, w_hm, b_hm, out_hm, N, 128, H4 * W4, 17, 0);
    // 12. paf = conv1x1(p2; 128->32) @96
    conv1x1_kernel<<<nblk((long)N * 32 * (H4 * W4 / 4)), BS, 0, stream>>>(
        p2, w_paf, b_paf, out_paf, N, 128, H4 * W4, 32, 0);
    // 13. peaks @96
    peaks_kernel<<<nblk((long)N * 17 * H4 * W4), BS, 0, stream>>>(
        out_hm, out_peaks, N * 17, H4, W4, 0.1f);
}